// Round 5
// baseline (232.537 us; speedup 1.0000x reference)
//
#include <hip/hip_runtime.h>

// Local windowed 2D autocorrelation.
// x: [8, 64, 128, 128] fp32; out: [8, 64, 31, 31, 8, 8] fp32.
// KH=KW=8, SH=SW=4, no padding.
//
// Decomposition (round 5 = round 4 + compile fix):
//  - block = 320 threads = 5 waves; wave k in 0..4 computes output row oy=k
//    for 62 windows (31 w-positions x 2 window-rows). Rows 5..7 of the output
//    come from the autocorr symmetry corr(dy,dx)=corr(-dy,-dx): row 8-k is
//    [edge, reverse(row k [1..7])], edge computed in the same loop.
//  - wave-uniform oy: no masked FMA issue (round 3 wasted 2.2x issue on
//    exec-masked lanes), uniform trip counts, contiguous per-wave loads.
//  - rolling buffer of D+1 rows (D=4-k), all compile-time indexed -> pure
//    registers (rounds 1-2 spilled with 64+ float window + accs live).
//  - 16 float4 loads per thread total (each window row loaded once), served
//    from L1 (block working set 6 KB).
//  - nontemporal stores via clang ext_vector float4 (HIP float4 is a class
//    type the builtin rejects -- round 4 compile failure).

#define NH 31
#define NW 31

typedef float f32x4 __attribute__((ext_vector_type(4)));

__device__ __forceinline__ void loadrow(const float* p, float r[8]) {
  f32x4 a = *reinterpret_cast<const f32x4*>(p);
  f32x4 b = *reinterpret_cast<const f32x4*>(p + 4);
  r[0] = a.x; r[1] = a.y; r[2] = a.z; r[3] = a.w;
  r[4] = b.x; r[5] = b.y; r[6] = b.z; r[7] = b.w;
}

// Task for dy = -D (output row oy = 4-D), D in 1..4.
// acc[ox] = sum_{i=D..7} sum_j W[i][j] * W[i-D][j+ox-4]
// e (if WE) = sum_{i=D..7} sum_{j=4..7} W[i-D][j] * W[i][j-4]   (mirror edge)
template <int D, bool WE>
__device__ __forceinline__ void corr_task(const float* src, float acc[8], float& e) {
  float R[D + 1][8];
#pragma unroll
  for (int i = 0; i < 8; ++i) {
    const int ca = i % (D + 1);
    loadrow(src + i * 128, R[ca]);
    if (i >= D) {
      const int cb = (i - D) % (D + 1);
#pragma unroll
      for (int ox = 0; ox < 8; ++ox) {
#pragma unroll
        for (int j = 0; j < 8; ++j) {
          const int jj = j + ox - 4;
          if (jj < 0 || jj > 7) continue;  // compile-time after unroll
          acc[ox] += R[ca][j] * R[cb][jj];
        }
      }
      if (WE) {
#pragma unroll
        for (int j = 4; j < 8; ++j) e += R[cb][j] * R[ca][j - 4];
      }
    }
  }
}

// dy = 0 task: acc[ox] for ox=0..4 (row 4 is self-mirrored).
__device__ __forceinline__ void corr_task0(const float* src, float acc[5]) {
  float r[8];
#pragma unroll
  for (int i = 0; i < 8; ++i) {
    loadrow(src + i * 128, r);
#pragma unroll
    for (int ox = 0; ox < 5; ++ox) {
#pragma unroll
      for (int j = 0; j < 8; ++j) {
        const int jj = j + ox - 4;
        if (jj < 0 || jj > 7) continue;
        acc[ox] += r[j] * r[jj];
      }
    }
  }
}

__device__ __forceinline__ void st4(float* p, float a, float b, float c, float d) {
  f32x4 v = {a, b, c, d};
  __builtin_nontemporal_store(v, reinterpret_cast<f32x4*>(p));
}

__global__ __launch_bounds__(320) void lacorr2d_kernel(
    const float* __restrict__ x, float* __restrict__ out) {
  const int wave = threadIdx.x >> 6;   // 0..4 : oy task
  const int lane = threadIdx.x & 63;
  const int w    = lane & 31;          // window col (31 = dead lane)
  const int hh   = lane >> 5;          // 0/1 within window-row pair
  const int hp   = blockIdx.x & 15;    // window-row pair
  const int bc   = blockIdx.x >> 4;    // 0..511
  const int h    = hp * 2 + hh;        // 0..31 (31 invalid)
  const bool valid = (w < NW) && (h < NH);
  const int hc = valid ? h : 0;
  const int wc = valid ? w : 0;

  const float* src = x + (size_t)bc * (128 * 128) + (size_t)(hc * 4) * 128 + wc * 4;
  float* dst = out + ((size_t)(bc * NH + hc) * NW + wc) * 64;

  float acc[8] = {0.f, 0.f, 0.f, 0.f, 0.f, 0.f, 0.f, 0.f};
  float e = 0.f;

  if (wave == 0) {                     // oy=0, dy=-4 (unpaired row)
    corr_task<4, false>(src, acc, e);
    if (valid) {
      st4(dst,     acc[0], acc[1], acc[2], acc[3]);
      st4(dst + 4, acc[4], acc[5], acc[6], acc[7]);
    }
  } else if (wave == 1) {              // oy=1 & mirror oy=7
    corr_task<3, true>(src, acc, e);
    if (valid) {
      st4(dst + 8,  acc[0], acc[1], acc[2], acc[3]);
      st4(dst + 12, acc[4], acc[5], acc[6], acc[7]);
      st4(dst + 56, e,      acc[7], acc[6], acc[5]);
      st4(dst + 60, acc[4], acc[3], acc[2], acc[1]);
    }
  } else if (wave == 2) {              // oy=2 & mirror oy=6
    corr_task<2, true>(src, acc, e);
    if (valid) {
      st4(dst + 16, acc[0], acc[1], acc[2], acc[3]);
      st4(dst + 20, acc[4], acc[5], acc[6], acc[7]);
      st4(dst + 48, e,      acc[7], acc[6], acc[5]);
      st4(dst + 52, acc[4], acc[3], acc[2], acc[1]);
    }
  } else if (wave == 3) {              // oy=3 & mirror oy=5
    corr_task<1, true>(src, acc, e);
    if (valid) {
      st4(dst + 24, acc[0], acc[1], acc[2], acc[3]);
      st4(dst + 28, acc[4], acc[5], acc[6], acc[7]);
      st4(dst + 40, e,      acc[7], acc[6], acc[5]);
      st4(dst + 44, acc[4], acc[3], acc[2], acc[1]);
    }
  } else {                             // oy=4, dy=0 (self-mirrored row)
    float a5[5] = {0.f, 0.f, 0.f, 0.f, 0.f};
    corr_task0(src, a5);
    if (valid) {
      st4(dst + 32, a5[0], a5[1], a5[2], a5[3]);
      st4(dst + 36, a5[4], a5[3], a5[2], a5[1]);
    }
  }
}

extern "C" void kernel_launch(void* const* d_in, const int* in_sizes, int n_in,
                              void* d_out, int out_size, void* d_ws, size_t ws_size,
                              hipStream_t stream) {
  const float* x = (const float*)d_in[0];
  float* out = (float*)d_out;
  // 512 bc-planes x 16 window-row pairs
  lacorr2d_kernel<<<512 * 16, 320, 0, stream>>>(x, out);
}

// Round 6
// 61.120 us; speedup vs baseline: 3.8046x; 3.8046x over previous
//
#include <hip/hip_runtime.h>

// Local windowed 2D autocorrelation.
// x: [8, 64, 128, 128] fp32; out: [8, 64, 31, 31, 8, 8] fp32.
// KH=KW=8, SH=SW=4, no padding.
//
// Round 6 = round 5 compute + LDS output assembly.
//  - block = 320 threads = 5 waves; wave k in 0..4 computes output row oy=k
//    for 62 windows (31 w-positions x 2 window-rows); rows 5..7 from the
//    autocorr symmetry corr(dy,dx)=corr(-dy,-dx) (reversal + 1 edge value).
//  - Round 5 lesson: scattered 32 B per-wave stores caused 3.75x HBM write
//    amplification (461 MB for a 123 MB output) -> writes are now assembled
//    in LDS (15.9 KB/block) and streamed out as contiguous full-line float4
//    runs by the whole block.
//  - LDS float4 slot index XOR-swizzled by (w&7): the window stride (256 B)
//    would otherwise make the compute-phase writes an 8-way bank conflict;
//    swizzle makes both the scattered writes and linear reads conflict-free.

#define NH 31
#define NW 31

typedef float f32x4 __attribute__((ext_vector_type(4)));

__device__ __forceinline__ void loadrow(const float* p, float r[8]) {
  f32x4 a = *reinterpret_cast<const f32x4*>(p);
  f32x4 b = *reinterpret_cast<const f32x4*>(p + 4);
  r[0] = a.x; r[1] = a.y; r[2] = a.z; r[3] = a.w;
  r[4] = b.x; r[5] = b.y; r[6] = b.z; r[7] = b.w;
}

// Task for dy = -D (output row oy = 4-D), D in 1..4.
// acc[ox] = sum_{i=D..7} sum_j W[i][j] * W[i-D][j+ox-4]
// e (if WE) = sum_{i=D..7} sum_{j=4..7} W[i-D][j] * W[i][j-4]   (mirror edge)
template <int D, bool WE>
__device__ __forceinline__ void corr_task(const float* src, float acc[8], float& e) {
  float R[D + 1][8];
#pragma unroll
  for (int i = 0; i < 8; ++i) {
    const int ca = i % (D + 1);
    loadrow(src + i * 128, R[ca]);
    if (i >= D) {
      const int cb = (i - D) % (D + 1);
#pragma unroll
      for (int ox = 0; ox < 8; ++ox) {
#pragma unroll
        for (int j = 0; j < 8; ++j) {
          const int jj = j + ox - 4;
          if (jj < 0 || jj > 7) continue;  // compile-time after unroll
          acc[ox] += R[ca][j] * R[cb][jj];
        }
      }
      if (WE) {
#pragma unroll
        for (int j = 4; j < 8; ++j) e += R[cb][j] * R[ca][j - 4];
      }
    }
  }
}

// dy = 0 task: acc[ox] for ox=0..4 (row 4 is self-mirrored).
__device__ __forceinline__ void corr_task0(const float* src, float acc[5]) {
  float r[8];
#pragma unroll
  for (int i = 0; i < 8; ++i) {
    loadrow(src + i * 128, r);
#pragma unroll
    for (int ox = 0; ox < 5; ++ox) {
#pragma unroll
      for (int j = 0; j < 8; ++j) {
        const int jj = j + ox - 4;
        if (jj < 0 || jj > 7) continue;
        acc[ox] += r[j] * r[jj];
      }
    }
  }
}

__global__ __launch_bounds__(320) void lacorr2d_kernel(
    const float* __restrict__ x, float* __restrict__ out) {
  __shared__ __align__(16) float lds[2][31][64];

  const int wave = threadIdx.x >> 6;   // 0..4 : oy task
  const int lane = threadIdx.x & 63;
  const int w    = lane & 31;          // window col (31 = dead lane)
  const int hh   = lane >> 5;          // 0/1 within window-row pair
  const int hp   = blockIdx.x & 15;    // window-row pair
  const int bc   = blockIdx.x >> 4;    // 0..511
  const int h    = hp * 2 + hh;        // 0..31 (31 invalid)
  const bool valid = (w < NW) && (h < NH);
  const int hc = valid ? h : 0;
  const int wc = valid ? w : 0;

  const float* src = x + (size_t)bc * (128 * 128) + (size_t)(hc * 4) * 128 + wc * 4;
  float* wbase = &lds[hh][wc][0];
  const int sw = wc & 7;  // swizzle key

  float acc[8] = {0.f, 0.f, 0.f, 0.f, 0.f, 0.f, 0.f, 0.f};
  float e = 0.f;

#define LDS_ST(e4, a, b, c, d)                                              \
  do {                                                                      \
    f32x4 v_ = {a, b, c, d};                                                \
    *reinterpret_cast<f32x4*>(wbase + (((e4) ^ sw) << 2)) = v_;             \
  } while (0)

  if (wave == 0) {                     // oy=0, dy=-4 (unpaired row)
    corr_task<4, false>(src, acc, e);
    if (valid) {
      LDS_ST(0, acc[0], acc[1], acc[2], acc[3]);
      LDS_ST(1, acc[4], acc[5], acc[6], acc[7]);
    }
  } else if (wave == 1) {              // oy=1 & mirror oy=7
    corr_task<3, true>(src, acc, e);
    if (valid) {
      LDS_ST(2,  acc[0], acc[1], acc[2], acc[3]);
      LDS_ST(3,  acc[4], acc[5], acc[6], acc[7]);
      LDS_ST(14, e,      acc[7], acc[6], acc[5]);
      LDS_ST(15, acc[4], acc[3], acc[2], acc[1]);
    }
  } else if (wave == 2) {              // oy=2 & mirror oy=6
    corr_task<2, true>(src, acc, e);
    if (valid) {
      LDS_ST(4,  acc[0], acc[1], acc[2], acc[3]);
      LDS_ST(5,  acc[4], acc[5], acc[6], acc[7]);
      LDS_ST(12, e,      acc[7], acc[6], acc[5]);
      LDS_ST(13, acc[4], acc[3], acc[2], acc[1]);
    }
  } else if (wave == 3) {              // oy=3 & mirror oy=5
    corr_task<1, true>(src, acc, e);
    if (valid) {
      LDS_ST(6,  acc[0], acc[1], acc[2], acc[3]);
      LDS_ST(7,  acc[4], acc[5], acc[6], acc[7]);
      LDS_ST(10, e,      acc[7], acc[6], acc[5]);
      LDS_ST(11, acc[4], acc[3], acc[2], acc[1]);
    }
  } else {                             // oy=4, dy=0 (self-mirrored row)
    float a5[5] = {0.f, 0.f, 0.f, 0.f, 0.f};
    corr_task0(src, a5);
    if (valid) {
      LDS_ST(8, a5[0], a5[1], a5[2], a5[3]);
      LDS_ST(9, a5[4], a5[3], a5[2], a5[1]);
    }
  }
#undef LDS_ST

  __syncthreads();

  // Stream the assembled tile to global: two contiguous 7936 B runs
  // (31 windows x 256 B each), full cache lines, lane-consecutive float4s.
#pragma unroll
  for (int h2 = 0; h2 < 2; ++h2) {
    const int hrow = hp * 2 + h2;
    if (hrow >= NH) continue;  // block-uniform
    float* orun = out + (size_t)(bc * NH + hrow) * NW * 64;
    for (int idx = threadIdx.x; idx < NW * 16; idx += 320) {
      const int ww = idx >> 4;
      const int e4 = idx & 15;
      f32x4 v = *reinterpret_cast<const f32x4*>(&lds[h2][ww][(e4 ^ (ww & 7)) << 2]);
      __builtin_nontemporal_store(v, reinterpret_cast<f32x4*>(orun + idx * 4));
    }
  }
}

extern "C" void kernel_launch(void* const* d_in, const int* in_sizes, int n_in,
                              void* d_out, int out_size, void* d_ws, size_t ws_size,
                              hipStream_t stream) {
  const float* x = (const float*)d_in[0];
  float* out = (float*)d_out;
  // 512 bc-planes x 16 window-row pairs
  lacorr2d_kernel<<<512 * 16, 320, 0, stream>>>(x, out);
}